// Round 2
// baseline (201.687 us; speedup 1.0000x reference)
//
#include <hip/hip_runtime.h>
#include <stdint.h>

typedef unsigned short u16;
typedef __attribute__((ext_vector_type(8))) short short8;   // 8 bf16 (4 VGPRs) — MFMA A/B frag
typedef __attribute__((ext_vector_type(4))) float float4v;  // MFMA C/D frag

__device__ __forceinline__ u16 f2bf(float f) {
    union { float f; uint32_t u; } v; v.f = f;
    uint32_t r = v.u + 0x7fffu + ((v.u >> 16) & 1u);  // RNE
    return (u16)(r >> 16);
}

__device__ __forceinline__ void gload16(const u16* g, u16* l) {
    __builtin_amdgcn_global_load_lds(
        (const __attribute__((address_space(1))) void*)g,
        (__attribute__((address_space(3))) void*)l, 16, 0, 0);
}

__device__ __forceinline__ float load_wn(const float* wts, float* wn) {
    float s = 0.f;
    #pragma unroll
    for (int e = 0; e < 8; ++e) { wn[e] = wts[e]; s += wn[e]; }
    return 1.0f / s;
}

// merge one 32x32 tile: W [E=8,K,N] f32 -> Wt [N,K] bf16, Wt[o*K+i] = sum_e wn_e W[e,i,o]
__device__ __forceinline__ void merge_tile(
    const float* __restrict__ W, u16* __restrict__ Wt, int K, int N, int lb,
    const float* wn, float inv, float (*tile)[33], int tid) {
    const int ntiles = N >> 5;
    const int o0 = (lb % ntiles) * 32, i0 = (lb / ntiles) * 32;
    const int tx = tid & 31, ty = tid >> 5;
    #pragma unroll
    for (int s4 = 0; s4 < 4; ++s4) {
        int il = ty + s4 * 8;
        float acc = 0.f;
        #pragma unroll
        for (int e = 0; e < 8; ++e)
            acc += wn[e] * W[(size_t)e * K * N + (size_t)(i0 + il) * N + o0 + tx];
        tile[il][tx] = acc * inv;
    }
    __syncthreads();
    #pragma unroll
    for (int s4 = 0; s4 < 4; ++s4) {
        int ol = ty + s4 * 8;
        Wt[(size_t)(o0 + ol) * K + i0 + tx] = f2bf(tile[tx][ol]);
    }
}

// ---------------- prep: x->bf16 | W0 merge | bias merge ----------------
// block ranges: [0,4096) cvt | [4096,4608) W0 | [4608,4618) bias
__global__ __launch_bounds__(256) void prep_fused(
    const float* __restrict__ x, u16* __restrict__ xbf,
    const float* __restrict__ wts,
    const float* __restrict__ W0, u16* __restrict__ W0t,
    const float* __restrict__ b0, const float* __restrict__ b1, const float* __restrict__ b2,
    float* __restrict__ bm) {
    __shared__ float tile[32][33];
    const int b = blockIdx.x, tid = threadIdx.x;

    if (b < 4096) {                       // ---- x -> bf16, 4 elem/thread ----
        int i = (b * 256 + tid) * 4;
        float4 v = *(const float4*)(x + i);
        union { u16 s[4]; uint64_t q; } o;
        o.s[0] = f2bf(v.x); o.s[1] = f2bf(v.y); o.s[2] = f2bf(v.z); o.s[3] = f2bf(v.w);
        *(uint64_t*)(xbf + i) = o.q;
        return;
    }

    float wn[8]; const float inv = load_wn(wts, wn);

    if (b < 4608) {                       // ---- W0 merge+transpose ----
        merge_tile(W0, W0t, 512, 1024, b - 4096, wn, inv, tile, tid);
        return;
    }

    // ---- bias merge: 2560 outputs ----
    int t = (b - 4608) * 256 + tid;
    if (t >= 2560) return;
    const float* bp; int o, stride;
    if (t < 1024)      { bp = b0; o = t;        stride = 1024; }
    else if (t < 2048) { bp = b1; o = t - 1024; stride = 1024; }
    else               { bp = b2; o = t - 2048; stride = 512;  }
    float acc = 0.f;
    #pragma unroll
    for (int e = 0; e < 8; ++e) acc += wn[e] * bp[e * stride + o];
    bm[t] = acc * inv;
}

// ------------- GEMM + bias + PReLU, 2-phase double-buffered pipeline -------------
// A [M,K] bf16 row-major, Bt [N,K] bf16 (B^T), out [M,N].
// BM=128 x BN(64|128) tile, BK=64, 256 thr = 4 waves in 2(M)x2(N).
// Double-buffered LDS (T3 "minimum 2-phase" recipe): per K-step —
//   __syncthreads() (drains prev prefetch: it had a full compute phase to land)
//   -> issue global_load_lds for tile t+1 into buf^1 (stays in flight)
//   -> ds_read + MFMA on buf (overlaps the in-flight loads)
// ONE barrier per K-step; no prefetch ever crosses a __syncthreads drain exposed.
// XOR chunk swizzle at the GLOBAL source address during staging (LDS lane-contiguous
// per global_load_lds constraint), mirrored on ds_read -> 2-way (free, m136).
// MERGE: tail blocks (bid >= nGemm) merge the NEXT layer's expert weights, overlapping
// that 16-32 MB f32 read with this layer's MFMA compute.
template <int BN, bool OUT_F32, bool MERGE>
__global__ __launch_bounds__(256, 2) void gemm_bias_prelu(
    const u16* __restrict__ A, const u16* __restrict__ Bt,
    const float* __restrict__ bias, const float* __restrict__ alpha,
    void* __restrict__ outp, int M, int N, int K,
    const float* __restrict__ wts, const float* __restrict__ Wm,
    u16* __restrict__ Wmt, int K2, int N2) {
    constexpr int BUFE = (128 + BN) * 64;            // u16 elems per buffer
    __shared__ __align__(16) u16 sh[2 * BUFE];       // 48 KB (BN=64) / 64 KB (BN=128)
    const int tid = threadIdx.x;
    const int nbn = N / BN;
    const int nGemm = nbn * (M >> 7);
    const int bid = blockIdx.x;

    if (MERGE && bid >= nGemm) {          // ---- fused weight merge for next layer ----
        float wn[8]; const float inv = load_wn(wts, wn);
        merge_tile(Wm, Wmt, K2, N2, bid - nGemm, wn, inv, (float(*)[33])(void*)sh, tid);
        return;
    }

    const int bn = bid % nbn, bm = bid / nbn;

    // staging: thread t, issue it -> LDS chunk (it*256 + t); row r = chunk/8, pos p = chunk%8
    const int r0 = tid >> 3;           // 0..31 (+32 per issue; (r&7) invariant)
    const int p  = tid & 7;
    const int c  = p ^ (r0 & 7);       // global k-chunk fetched into LDS pos p
    const u16* Ag = A  + (size_t)(bm * 128 + r0) * K + c * 8;
    const u16* Bg = Bt + (size_t)(bn * BN  + r0) * K + c * 8;

    const int lane = tid & 63, w = tid >> 6;
    constexpr int WN = BN / 2;         // wave tile N: 32 or 64
    constexpr int NI = WN / 16;        // 2 or 4
    const int wm = (w >> 1) * 64, wncol = (w & 1) * WN;
    const int l16 = lane & 15, quad = lane >> 4;
    const int xr = l16 & 7;            // (row&7) of every fragment row (offsets ≡ 0 mod 8,16,32,64)

    float4v acc[4][NI] = {};
    const int nk = K >> 6;

    // prologue: stage tile 0 into buffer 0
    {
        u16* Al = sh + tid * 8;
        u16* Bl = sh + 128 * 64 + tid * 8;
        #pragma unroll
        for (int it = 0; it < 4; ++it)
            gload16(Ag + (size_t)(it * 32) * K, Al + it * 2048);
        #pragma unroll
        for (int it = 0; it < BN / 32; ++it)
            gload16(Bg + (size_t)(it * 32) * K, Bl + it * 2048);
    }
    Ag += 64; Bg += 64;

    int cur = 0;
    for (int kt = 0; kt < nk; ++kt) {
        __syncthreads();               // implicit vmcnt(0): buf[cur] ready for all waves

        if (kt + 1 < nk) {             // issue next-tile loads into buf^1 (in flight under MFMA)
            u16* Al = sh + (cur ^ 1) * BUFE + tid * 8;
            u16* Bl = sh + (cur ^ 1) * BUFE + 128 * 64 + tid * 8;
            #pragma unroll
            for (int it = 0; it < 4; ++it)
                gload16(Ag + (size_t)(it * 32) * K, Al + it * 2048);
            #pragma unroll
            for (int it = 0; it < BN / 32; ++it)
                gload16(Bg + (size_t)(it * 32) * K, Bl + it * 2048);
            Ag += 64; Bg += 64;
        }

        const short8* A8 = (const short8*)(sh + cur * BUFE);
        const short8* B8 = (const short8*)(sh + cur * BUFE + 128 * 64);
        #pragma unroll
        for (int kk = 0; kk < 2; ++kk) {
            const int cb = kk * 4;
            short8 af[4], bf[NI];
            #pragma unroll
            for (int mi = 0; mi < 4; ++mi)
                af[mi] = A8[(wm + mi * 16 + l16) * 8 + ((cb + quad) ^ xr)];
            #pragma unroll
            for (int ni = 0; ni < NI; ++ni)
                bf[ni] = B8[(wncol + ni * 16 + l16) * 8 + ((cb + quad) ^ xr)];
            #pragma unroll
            for (int mi = 0; mi < 4; ++mi)
                #pragma unroll
                for (int ni = 0; ni < NI; ++ni)
                    acc[mi][ni] = __builtin_amdgcn_mfma_f32_16x16x32_bf16(
                        af[mi], bf[ni], acc[mi][ni], 0, 0, 0);
        }
        cur ^= 1;
    }

    // epilogue: C/D layout col=lane&15, row=quad*4+reg  [m89/m91]
    const int cbase = bn * BN + wncol + l16;
    float bv[NI], av[NI];
    #pragma unroll
    for (int ni = 0; ni < NI; ++ni) { bv[ni] = bias[cbase + ni * 16]; av[ni] = alpha[cbase + ni * 16]; }
    const int rbase = bm * 128 + wm + quad * 4;
    #pragma unroll
    for (int mi = 0; mi < 4; ++mi) {
        #pragma unroll
        for (int reg = 0; reg < 4; ++reg) {
            int r = rbase + mi * 16 + reg;
            #pragma unroll
            for (int ni = 0; ni < NI; ++ni) {
                float v = acc[mi][ni][reg] + bv[ni];
                v = v >= 0.f ? v : av[ni] * v;
                size_t idx = (size_t)r * N + cbase + ni * 16;
                if (OUT_F32) ((float*)outp)[idx] = v;
                else         ((u16*)outp)[idx] = f2bf(v);
            }
        }
    }
}

extern "C" void kernel_launch(void* const* d_in, const int* in_sizes, int n_in,
                              void* d_out, int out_size, void* d_ws, size_t ws_size,
                              hipStream_t stream) {
    const float* x   = (const float*)d_in[0];
    const float* wts = (const float*)d_in[1];
    const float* W0  = (const float*)d_in[2];
    const float* b0  = (const float*)d_in[3];
    const float* a0  = (const float*)d_in[4];
    const float* W1  = (const float*)d_in[5];
    const float* b1  = (const float*)d_in[6];
    const float* a1  = (const float*)d_in[7];
    const float* W2  = (const float*)d_in[8];
    const float* b2  = (const float*)d_in[9];
    const float* a2  = (const float*)d_in[10];
    float* out = (float*)d_out;

    char* ws = (char*)d_ws;
    u16*   xbf  = (u16*)ws;  ws += (size_t)8192 * 512 * 2;
    u16*   act1 = (u16*)ws;  ws += (size_t)8192 * 1024 * 2;
    u16*   act2 = (u16*)ws;  ws += (size_t)8192 * 1024 * 2;
    u16*   W0t  = (u16*)ws;  ws += (size_t)1024 * 512 * 2;
    u16*   W1t  = (u16*)ws;  ws += (size_t)1024 * 1024 * 2;
    u16*   W2t  = (u16*)ws;  ws += (size_t)512 * 1024 * 2;
    float* bm   = (float*)ws;  // 2560 floats

    // prep: 4096 cvt + 512 W0-merge + 10 bias = 4618 blocks (~41 MB traffic)
    prep_fused<<<4618, 256, 0, stream>>>(x, xbf, wts, W0, W0t, b0, b1, b2, bm);

    // L0: 512 gemm blocks (128x128) + 1024 W1-merge tail blocks (32 MB read overlapped)
    gemm_bias_prelu<128, false, true><<<512 + 1024, 256, 0, stream>>>(
        xbf, W0t, bm, a0, act1, 8192, 1024, 512,
        wts, W1, W1t, 1024, 1024);

    // L1: 512 gemm blocks (128x128) + 512 W2-merge tail blocks (16 MB read overlapped)
    gemm_bias_prelu<128, false, true><<<512 + 512, 256, 0, stream>>>(
        act1, W1t, bm + 1024, a1, act2, 8192, 1024, 1024,
        wts, W2, W2t, 1024, 512);

    // L2: N=512 -> 128x64 tile for block count (512 blocks), f32 out
    gemm_bias_prelu<64, true, false><<<512, 256, 0, stream>>>(
        act2, W2t, bm + 2048, a2, out, 8192, 512, 1024,
        nullptr, nullptr, nullptr, 0, 0);
}

// Round 4
// 194.533 us; speedup vs baseline: 1.0368x; 1.0368x over previous
//
#include <hip/hip_runtime.h>
#include <stdint.h>

typedef unsigned short u16;
typedef __attribute__((ext_vector_type(8))) short short8;   // 8 bf16 (4 VGPRs) — MFMA A/B frag
typedef __attribute__((ext_vector_type(4))) float float4v;  // MFMA C/D frag

__device__ __forceinline__ u16 f2bf(float f) {
    union { float f; uint32_t u; } v; v.f = f;
    uint32_t r = v.u + 0x7fffu + ((v.u >> 16) & 1u);  // RNE
    return (u16)(r >> 16);
}

__device__ __forceinline__ void gload16(const u16* g, u16* l) {
    __builtin_amdgcn_global_load_lds(
        (const __attribute__((address_space(1))) void*)g,
        (__attribute__((address_space(3))) void*)l, 16, 0, 0);
}

__device__ __forceinline__ float load_wn(const float* wts, float* wn) {
    float s = 0.f;
    #pragma unroll
    for (int e = 0; e < 8; ++e) { wn[e] = wts[e]; s += wn[e]; }
    return 1.0f / s;
}

// merge one 32x32 tile: W [E=8,K,N] f32 -> Wt [N,K] bf16, Wt[o*K+i] = sum_e wn_e W[e,i,o]
// (fresh block: no leading sync needed; internal sync separates write/read-back phases)
__device__ __forceinline__ void merge_tile(
    const float* __restrict__ W, u16* __restrict__ Wt, int K, int N, int lb,
    const float* wn, float inv, float (*tile)[33], int tid) {
    const int ntiles = N >> 5;
    const int o0 = (lb % ntiles) * 32, i0 = (lb / ntiles) * 32;
    const int tx = tid & 31, ty = tid >> 5;
    #pragma unroll
    for (int s4 = 0; s4 < 4; ++s4) {
        int il = ty + s4 * 8;
        float acc = 0.f;
        #pragma unroll
        for (int e = 0; e < 8; ++e)
            acc += wn[e] * W[(size_t)e * K * N + (size_t)(i0 + il) * N + o0 + tx];
        tile[il][tx] = acc * inv;
    }
    __syncthreads();
    #pragma unroll
    for (int s4 = 0; s4 < 4; ++s4) {
        int ol = ty + s4 * 8;
        Wt[(size_t)(o0 + ol) * K + i0 + tx] = f2bf(tile[tx][ol]);
    }
}

// ---------------- prep: W0 merge | x->bf16 | bias merge ----------------
// LPT order: heavy merge blocks FIRST so the dispatch tail is light cvt work.
// block ranges: [0,512) W0 | [512,4608) cvt | [4608,4618) bias
__global__ __launch_bounds__(256) void prep_fused(
    const float* __restrict__ x, u16* __restrict__ xbf,
    const float* __restrict__ wts,
    const float* __restrict__ W0, u16* __restrict__ W0t,
    const float* __restrict__ b0, const float* __restrict__ b1, const float* __restrict__ b2,
    float* __restrict__ bm) {
    __shared__ float tile[32][33];
    const int b = blockIdx.x, tid = threadIdx.x;

    if (b >= 512 && b < 4608) {           // ---- x -> bf16, 4 elem/thread ----
        int i = ((b - 512) * 256 + tid) * 4;
        float4 v = *(const float4*)(x + i);
        union { u16 s[4]; uint64_t q; } o;
        o.s[0] = f2bf(v.x); o.s[1] = f2bf(v.y); o.s[2] = f2bf(v.z); o.s[3] = f2bf(v.w);
        *(uint64_t*)(xbf + i) = o.q;
        return;
    }

    float wn[8]; const float inv = load_wn(wts, wn);

    if (b < 512) {                        // ---- W0 merge+transpose (heavy, first) ----
        merge_tile(W0, W0t, 512, 1024, b, wn, inv, tile, tid);
        return;
    }

    // ---- bias merge: 2560 outputs ----
    int t = (b - 4608) * 256 + tid;
    if (t >= 2560) return;
    const float* bp; int o, stride;
    if (t < 1024)      { bp = b0; o = t;        stride = 1024; }
    else if (t < 2048) { bp = b1; o = t - 1024; stride = 1024; }
    else               { bp = b2; o = t - 2048; stride = 512;  }
    float acc = 0.f;
    #pragma unroll
    for (int e = 0; e < 8; ++e) acc += wn[e] * bp[e * stride + o];
    bm[t] = acc * inv;
}

// ------------- GEMM + bias + PReLU, with optional fused weight-merge tail blocks ----
// A [M,K] bf16 row-major, Bt [N,K] bf16 (B^T), out [M,N].
// BM=128 x BN(64|128) block tile, BK=64, 256 thr = 4 waves in 2(M)x2(N);
// BN=128: wave tile 64x64 = 4x4 MFMA 16x16x32 (m97 geometry). BN=64: 4x2 (L2, N=512).
// XOR chunk swizzle at the GLOBAL source address during staging (LDS stays
// lane-contiguous per global_load_lds constraint), mirrored on ds_read -> 2-way (free).
// MERGE: tail blocks (bid >= nGemm) merge BOTH later layers' expert weights (W1, W2),
// overlapping that 48 MB f32 read with L0's MFMA compute; L1/L2 dispatch clean.
template <int BN, bool OUT_F32, bool MERGE>
__global__ __launch_bounds__(256, 2) void gemm_bias_prelu(
    const u16* __restrict__ A, const u16* __restrict__ Bt,
    const float* __restrict__ bias, const float* __restrict__ alpha,
    void* __restrict__ outp, int M, int N, int K,
    const float* __restrict__ wts,
    const float* __restrict__ WmA, u16* __restrict__ WmAt, int KA, int NA, int nTilesA,
    const float* __restrict__ WmB, u16* __restrict__ WmBt, int KB, int NB) {
    __shared__ __align__(16) u16 sh[(128 + BN) * 64];   // 24 KB (BN=64) / 32 KB (BN=128)
    const int tid = threadIdx.x;
    const int nbn = N / BN;
    const int nGemm = nbn * (M >> 7);
    const int bid = blockIdx.x;

    if (MERGE && bid >= nGemm) {          // ---- fused weight merge for later layers ----
        float wn[8]; const float inv = load_wn(wts, wn);
        const int idx = bid - nGemm;
        if (idx < nTilesA)
            merge_tile(WmA, WmAt, KA, NA, idx, wn, inv, (float(*)[33])(void*)sh, tid);
        else
            merge_tile(WmB, WmBt, KB, NB, idx - nTilesA, wn, inv, (float(*)[33])(void*)sh, tid);
        return;
    }

    const int bn = bid % nbn, bm = bid / nbn;
    u16* As = sh;
    u16* Bs = sh + 128 * 64;

    // staging: thread t, issue it -> LDS chunk (it*256 + t); row r = chunk/8, pos p = chunk%8
    const int r0 = tid >> 3;           // 0..31 (+32 per issue; (r&7) invariant)
    const int p  = tid & 7;
    const int c  = p ^ (r0 & 7);       // global k-chunk fetched into LDS pos p
    const u16* Ag = A  + (size_t)(bm * 128 + r0) * K + c * 8;
    const u16* Bg = Bt + (size_t)(bn * BN  + r0) * K + c * 8;
    u16* Al = As + tid * 8;
    u16* Bl = Bs + tid * 8;

    const int lane = tid & 63, w = tid >> 6;
    constexpr int WN = BN / 2;         // wave tile N: 32 or 64
    constexpr int NI = WN / 16;        // 2 or 4
    const int wm = (w >> 1) * 64, wncol = (w & 1) * WN;
    const int l16 = lane & 15, quad = lane >> 4;
    const int xr = l16 & 7;            // (row&7) of every fragment row (offsets ≡ 0 mod 8,16,32,64)
    const short8* As8 = (const short8*)As;
    const short8* Bs8 = (const short8*)Bs;

    float4v acc[4][NI] = {};

    const int nk = K >> 6;
    for (int kt = 0; kt < nk; ++kt) {
        #pragma unroll
        for (int it = 0; it < 4; ++it)
            gload16(Ag + (size_t)(it * 32) * K, Al + it * 2048);
        #pragma unroll
        for (int it = 0; it < BN / 32; ++it)
            gload16(Bg + (size_t)(it * 32) * K, Bl + it * 2048);
        __syncthreads();
        #pragma unroll
        for (int kk = 0; kk < 2; ++kk) {
            const int cb = kk * 4;
            short8 af[4], bf[NI];
            #pragma unroll
            for (int mi = 0; mi < 4; ++mi)
                af[mi] = As8[(wm + mi * 16 + l16) * 8 + ((cb + quad) ^ xr)];
            #pragma unroll
            for (int ni = 0; ni < NI; ++ni)
                bf[ni] = Bs8[(wncol + ni * 16 + l16) * 8 + ((cb + quad) ^ xr)];
            #pragma unroll
            for (int mi = 0; mi < 4; ++mi)
                #pragma unroll
                for (int ni = 0; ni < NI; ++ni)
                    acc[mi][ni] = __builtin_amdgcn_mfma_f32_16x16x32_bf16(
                        af[mi], bf[ni], acc[mi][ni], 0, 0, 0);
        }
        if (kt + 1 < nk) __syncthreads();
        Ag += 64; Bg += 64;
    }

    // epilogue: C/D layout col=lane&15, row=quad*4+reg  [m89/m91]
    const int cbase = bn * BN + wncol + l16;
    float bv[NI], av[NI];
    #pragma unroll
    for (int ni = 0; ni < NI; ++ni) { bv[ni] = bias[cbase + ni * 16]; av[ni] = alpha[cbase + ni * 16]; }
    const int rbase = bm * 128 + wm + quad * 4;
    #pragma unroll
    for (int mi = 0; mi < 4; ++mi) {
        #pragma unroll
        for (int reg = 0; reg < 4; ++reg) {
            int r = rbase + mi * 16 + reg;
            #pragma unroll
            for (int ni = 0; ni < NI; ++ni) {
                float v = acc[mi][ni][reg] + bv[ni];
                v = v >= 0.f ? v : av[ni] * v;
                size_t idx = (size_t)r * N + cbase + ni * 16;
                if (OUT_F32) ((float*)outp)[idx] = v;
                else         ((u16*)outp)[idx] = f2bf(v);
            }
        }
    }
}

extern "C" void kernel_launch(void* const* d_in, const int* in_sizes, int n_in,
                              void* d_out, int out_size, void* d_ws, size_t ws_size,
                              hipStream_t stream) {
    const float* x   = (const float*)d_in[0];
    const float* wts = (const float*)d_in[1];
    const float* W0  = (const float*)d_in[2];
    const float* b0  = (const float*)d_in[3];
    const float* a0  = (const float*)d_in[4];
    const float* W1  = (const float*)d_in[5];
    const float* b1  = (const float*)d_in[6];
    const float* a1  = (const float*)d_in[7];
    const float* W2  = (const float*)d_in[8];
    const float* b2  = (const float*)d_in[9];
    const float* a2  = (const float*)d_in[10];
    float* out = (float*)d_out;

    char* ws = (char*)d_ws;
    u16*   xbf  = (u16*)ws;  ws += (size_t)8192 * 512 * 2;
    u16*   act1 = (u16*)ws;  ws += (size_t)8192 * 1024 * 2;
    u16*   act2 = (u16*)ws;  ws += (size_t)8192 * 1024 * 2;
    u16*   W0t  = (u16*)ws;  ws += (size_t)1024 * 512 * 2;
    u16*   W1t  = (u16*)ws;  ws += (size_t)1024 * 1024 * 2;
    u16*   W2t  = (u16*)ws;  ws += (size_t)512 * 1024 * 2;
    float* bm   = (float*)ws;  // 2560 floats

    // prep: 512 W0-merge (first, LPT) + 4096 cvt + 10 bias = 4618 blocks (~41 MB)
    prep_fused<<<4618, 256, 0, stream>>>(x, xbf, wts, W0, W0t, b0, b1, b2, bm);

    // L0: 512 gemm blocks (128x128) + 1536 merge tails (W1: 1024 tiles, W2: 512 tiles;
    //     48 MB f32 read overlapped under L0 compute)
    gemm_bias_prelu<128, false, true><<<512 + 1536, 256, 0, stream>>>(
        xbf, W0t, bm, a0, act1, 8192, 1024, 512,
        wts, W1, W1t, 1024, 1024, 1024, W2, W2t, 1024, 512);

    // L1: clean 512 gemm blocks (128x128)
    gemm_bias_prelu<128, false, false><<<512, 256, 0, stream>>>(
        act1, W1t, bm + 1024, a1, act2, 8192, 1024, 1024,
        nullptr, nullptr, nullptr, 0, 0, 0, nullptr, nullptr, 0, 0);

    // L2: N=512 -> 128x64 tile (512 blocks), f32 out
    gemm_bias_prelu<64, true, false><<<512, 256, 0, stream>>>(
        act2, W2t, bm + 2048, a2, out, 8192, 512, 1024,
        nullptr, nullptr, nullptr, 0, 0, 0, nullptr, nullptr, 0, 0);
}